// Round 3
// baseline (953.159 us; speedup 1.0000x reference)
//
#include <hip/hip_runtime.h>

// NodeDenoisingADMM: N=20000, FEAT=64, K=4, NNZ=320000, NU=2.0, GAMMA=1.0, J=3
// 14 scan iterations, output = final U (N,FEAT) fp32.
//
// State reduction (GAMMA=1): carried state is v alone.
//   S_t = W_k @ U_t ; Y_t = S_t + v_{t-1} ; Z_t = soft(S_t + Y_t, nu_k d)
//   v_t = Y_t - Z_t ; U_{t+1} = (dm*F - sum_k W_k v_k)/(dm+1), dm = d*mask^2
//
// Node-major CSR: rowid = n*K + k. Edge meta packed in 4 B:
//   [31] sign | [30:26] exp5 (bias 96, 0 => value 0) | [25:17] mant9 (RNE)
//   | [16:15] k | [14:0] col       (rel err 2^-11 < bf16 operand err)
// Scatter is XCD-FILTERED (8 buckets by row/2500, block handles bucket
// blockIdx%8) so cursor/cmeta dirty lines live in ONE XCD's L2.
// R3: all scatter INPUT loads are NON-TEMPORAL (clean streams must not evict
// the dirty cursor/cmeta lines -> kills the evict/refetch bounce that made
// WRITE_SIZE 51 MB for 5 MB of payload); rows read via u16 side copy
// (8-pass replication 41 MB -> 20.5 MB). cmeta is NT-read in iteration
// kernels (zero reuse) so U_bf/V_bf gather lines stay L2-resident.
// wtv is templated<LAST>: fp32 U store only on the final iteration
// (earlier iterations only feed U_bf) -> saves 13 x 5.12 MB of writes.
// R2: meta software pipeline — cmeta chunk for row r+1 issued before row
// r's gathers (removes ~200cy exposed latency per row). R1 NOTE: k-phasing
// wtv accumulation REGRESSES (4x per-segment overhead > L2 gain).
// Gather operands (U,V,F) are bf16 side copies; gathers batched for MLP.
// Accumulation order is fixed -> bit-identical across these variants.

constexpr int N_    = 20000;
constexpr int FEAT_ = 64;
constexpr int K_    = 4;
constexpr int NNZ_  = 320000;
constexpr int NF    = N_ * FEAT_;     // 1,280,000
constexpr int KN    = K_ * N_;        // 80,000 CSR rows
constexpr int NEDGE = K_ * NNZ_;      // 1,280,000
constexpr int NITER = 14;
constexpr int BLK   = 256;
constexpr int NSB   = (KN + 255) / 256;  // 313 scan blocks
constexpr int NCPY  = 8;                 // hist privatization copies
constexpr int NXCD  = 8;
constexpr int EPV   = 2048;              // edges per virtual scatter block
constexpr int NVB   = NEDGE / EPV;       // 625 virtual blocks

constexpr int R_SP  = 10;                          // CSR rows/wave, spmm
constexpr int NB_SP = ((KN + R_SP - 1) / R_SP + 3) / 4;   // 2000 blocks
constexpr int R_WT  = 4;                           // nodes/wave, wtv
constexpr int NB_WT = ((N_ + R_WT - 1) / R_WT + 3) / 4;   // 1250 blocks

__constant__ float c_nu[4] = {0.0f, 2.0f, 0.5f, 0.125f};

__device__ __forceinline__ float softf(float x, float t) {
    float a = fabsf(x) - t;
    a = a > 0.0f ? a : 0.0f;
    return copysignf(a, x);
}

__device__ __forceinline__ float bf2f(unsigned short u) {
    union { unsigned int i; float f; } x;
    x.i = ((unsigned int)u) << 16;
    return x.f;
}
__device__ __forceinline__ unsigned short f2bf(float f) {   // RNE
    union { float f; unsigned int i; } x;
    x.f = f;
    unsigned int r = x.i + 0x7FFFu + ((x.i >> 16) & 1u);
    return (unsigned short)(r >> 16);
}

__device__ __forceinline__ void decode_meta(unsigned int p, int& c, float& v) {
    c = (int)((p >> 15) & 3u) * N_ + (int)(p & 0x7FFFu);
    unsigned int e5 = (p >> 26) & 0x1Fu;
    unsigned int bits = (p & 0x80000000u) | ((e5 + 96u) << 23) |
                        (((p >> 17) & 0x1FFu) << 14);
    v = (e5 == 0u) ? 0.0f : __uint_as_float(bits);
}

// ---------------- CSR build + precompute ----------------

// dm[n] = d*mask^2 ; F_bf = bf16(F)
__global__ __launch_bounds__(BLK) void precompute_kernel(
    const float* __restrict__ F, const float* __restrict__ d,
    const float* __restrict__ mask, float* __restrict__ dm,
    unsigned short* __restrict__ F_bf) {
    int i = blockIdx.x * BLK + threadIdx.x;       // over NF/4
    if (i >= NF / 4) return;
    float4 f = ((const float4*)F)[i];
    ushort4 o;
    o.x = f2bf(f.x); o.y = f2bf(f.y); o.z = f2bf(f.z); o.w = f2bf(f.w);
    ((ushort4*)F_bf)[i] = o;
    if ((i & (FEAT_ / 4 - 1)) == 0) {
        int n = i / (FEAT_ / 4);
        dm[n] = d[n] * mask[n] * mask[n];
    }
}

// rowid = rows[e]*K + k ; privatized copies (blockIdx&7).
// Also emits the u16 rows side copy used by scatter (rows < 20000 < 65536).
__global__ __launch_bounds__(BLK) void hist_kernel(
    const int* __restrict__ rows, int* __restrict__ cnt8,
    unsigned short* __restrict__ rows16) {
    int e = blockIdx.x * BLK + threadIdx.x;
    if (e >= NEDGE) return;
    int row = __builtin_nontemporal_load(&rows[e]);
    rows16[e] = (unsigned short)row;
    int k = e / NNZ_;
    int copy = blockIdx.x & (NCPY - 1);
    atomicAdd(&cnt8[copy * KN + row * K_ + k], 1);
}

// block-local exclusive scan over summed copies + block sums
__global__ __launch_bounds__(256) void scan1_kernel(
    const int* __restrict__ cnt8, int* __restrict__ loc,
    int* __restrict__ bsum) {
    int i = blockIdx.x * 256 + threadIdx.x;
    int x = 0;
    if (i < KN) {
        #pragma unroll
        for (int c = 0; c < NCPY; ++c) x += cnt8[c * KN + i];
    }
    int lane = threadIdx.x & 63, wid = threadIdx.x >> 6;
    int v = x;
    #pragma unroll
    for (int off = 1; off < 64; off <<= 1) {
        int t = __shfl_up(v, off, 64);
        if (lane >= off) v += t;
    }
    __shared__ int ws[4];
    if (lane == 63) ws[wid] = v;
    __syncthreads();
    int add = 0;
    for (int u = 0; u < wid; ++u) add += ws[u];
    v += add;
    if (i < KN) loc[i] = v - x;
    if (threadIdx.x == 255) bsum[blockIdx.x] = v;
}

__global__ __launch_bounds__(512) void scan2_kernel(int* __restrict__ bsum) {
    int tid = threadIdx.x;
    int x = (tid < NSB) ? bsum[tid] : 0;
    int lane = tid & 63, wid = tid >> 6;
    int v = x;
    #pragma unroll
    for (int off = 1; off < 64; off <<= 1) {
        int t = __shfl_up(v, off, 64);
        if (lane >= off) v += t;
    }
    __shared__ int ws[8];
    if (lane == 63) ws[wid] = v;
    __syncthreads();
    int add = 0;
    for (int u = 0; u < wid; ++u) add += ws[u];
    v += add;
    if (tid < NSB) bsum[tid] = v - x;
}

__global__ __launch_bounds__(256) void scan3_kernel(
    const int* __restrict__ loc, const int* __restrict__ bsum,
    int* __restrict__ offs, int* __restrict__ cursor) {
    int i = blockIdx.x * 256 + threadIdx.x;
    if (i < KN) {
        int v = loc[i] + bsum[blockIdx.x];
        offs[i] = v;
        cursor[i] = v;
    }
    if (i == 0) offs[KN] = NEDGE;
}

// XCD-filtered scatter: block = (vb, xcd=blockIdx%8); processes edge slice
// [vb*EPV, (vb+1)*EPV) but ONLY edges with row/2500 == xcd. All input loads
// are NON-TEMPORAL so the clean streams don't evict dirty cursor/cmeta
// lines from this XCD's L2 (the evict->writeback->refetch bounce was 46 MB
// of excess WRITE_SIZE). Correct for ANY block->XCD mapping.
__global__ __launch_bounds__(BLK) void scatter_kernel(
    const unsigned short* __restrict__ rows16, const int* __restrict__ cols,
    const float* __restrict__ vals, int* __restrict__ cursor,
    unsigned int* __restrict__ cmeta) {
    int xcd = blockIdx.x & (NXCD - 1);
    int vb  = blockIdx.x >> 3;
    int ebase = vb * EPV;
    #pragma unroll
    for (int i = 0; i < EPV / BLK; ++i) {
        int e = ebase + i * BLK + threadIdx.x;
        int row = (int)__builtin_nontemporal_load(&rows16[e]);
        if (row / (N_ / NXCD) != xcd) continue;
        int k = e / NNZ_;
        float val = __builtin_nontemporal_load(&vals[e]);
        int   col = __builtin_nontemporal_load(&cols[e]);
        unsigned int b  = __float_as_uint(val);
        unsigned int rb = b + 0x1FFFu + ((b >> 14) & 1u);  // RNE to 9 mant
        int exp8 = (int)((rb >> 23) & 0xFF);
        unsigned int pk = 0u;
        if (exp8 > 96)                                     // else flush to 0
            pk = (b & 0x80000000u) | ((unsigned int)(exp8 - 96) << 26) |
                 (((rb >> 14) & 0x1FFu) << 17);
        pk |= ((unsigned int)k << 15) | (unsigned int)col;
        int pos = atomicAdd(&cursor[row * K_ + k], 1);
        cmeta[pos] = pk;
    }
}

// ---------------- iteration kernels ----------------

// Accumulate one <=64-edge chunk whose packed meta is ALREADY decoded into
// per-lane (c_l, v_l); lanes >= n hold (padc, 0). bf16 gather (ushort4),
// fp32 FMA, gathers batched BATCH-deep for memory-level parallelism.
template <int BATCH>
__device__ __forceinline__ void chunk_accum(
    int c_l, float v_l, int n, const ushort4* __restrict__ Xb,
    int sub, int q, float4& acc) {
    int iters = (n + 3) >> 2;
    int itersPad = (iters + BATCH - 1) & ~(BATCH - 1);  // <= 16
    for (int it0 = 0; it0 < itersPad; it0 += BATCH) {
        float   vv[BATCH];
        ushort4 xx[BATCH];
        #pragma unroll
        for (int u = 0; u < BATCH; ++u) {
            int j = 4 * (it0 + u) + sub;      // < 64
            int   c = __shfl(c_l, j, 64);
            vv[u]   = __shfl(v_l, j, 64);
            xx[u]   = Xb[c * (FEAT_ / 4) + q];
        }
        #pragma unroll
        for (int u = 0; u < BATCH; ++u) {
            acc.x += vv[u] * bf2f(xx[u].x);
            acc.y += vv[u] * bf2f(xx[u].y);
            acc.z += vv[u] * bf2f(xx[u].z);
            acc.w += vv[u] * bf2f(xx[u].w);
        }
    }
}

// Fallback (not pipelined): load+decode+accumulate windows [beg,end).
// Only runs for rare overflow chunks beyond the prefetched ones.
template <int BATCH>
__device__ __forceinline__ void tail_accum(
    const unsigned int* __restrict__ cmeta, const ushort4* __restrict__ Xb,
    int beg, int end, int lane, int sub, int q, int padc, float4& acc) {
    for (int eb = beg; eb < end; eb += 64) {
        int n = end - eb;
        if (n > 64) n = 64;
        int   c_l = padc;
        float v_l = 0.0f;
        if (lane < n) {
            unsigned int p = __builtin_nontemporal_load(&cmeta[eb + lane]);
            decode_meta(p, c_l, v_l);
        }
        chunk_accum<BATCH>(c_l, v_l, n, Xb, sub, q, acc);
    }
}

__device__ __forceinline__ void butterfly4(float4& a) {
    #pragma unroll
    for (int m = 16; m <= 32; m <<= 1) {
        a.x += __shfl_xor(a.x, m, 64);
        a.y += __shfl_xor(a.y, m, 64);
        a.z += __shfl_xor(a.z, m, 64);
        a.w += __shfl_xor(a.w, m, 64);
    }
}

// wave per R_SP contiguous CSR rows (rowid = n*K+k); acc = (W_k @ X)[n];
// fused v-update into bf16 V_bf (layout [k][n]). FIRST: Y=0, X=F_bf.
// Meta for row r+1 prefetched (NT: zero reuse) during row r.
template <bool FIRST>
__global__ __launch_bounds__(BLK) void spmm_fused_kernel(
    const int* __restrict__ offs, const unsigned int* __restrict__ cmeta,
    const unsigned short* __restrict__ Xb,
    const float* __restrict__ d, unsigned short* __restrict__ V_bf) {
    int wave = (blockIdx.x * BLK + threadIdx.x) >> 6;
    int lane = threadIdx.x & 63;
    int sub  = lane >> 4, q = lane & 15;
    int base = wave * R_SP;
    if (base >= KN) return;
    int off_l = 0;
    if (lane <= R_SP) {
        int i = base + lane;
        if (i > KN) i = KN;
        off_l = offs[i];
    }
    const ushort4* X4 = (const ushort4*)Xb;
    ushort4* V4 = (ushort4*)V_bf;

    // prefetch row 0 meta (first chunk)
    unsigned int p_cur = 0u;
    {
        int b0 = __shfl(off_l, 0, 64), e0 = __shfl(off_l, 1, 64);
        int nn = e0 - b0;
        if (nn > 64) nn = 64;
        if (lane < nn) p_cur = __builtin_nontemporal_load(&cmeta[b0 + lane]);
    }
    for (int r = 0; r < R_SP; ++r) {
        int w = base + r;                // rowid = n*K + k
        if (w >= KN) break;
        int k = w & (K_ - 1);
        int n = w >> 2;
        int beg = __shfl(off_l, r, 64);
        int end = __shfl(off_l, r + 1, 64);
        // issue next row's meta load (overlaps this row's gathers)
        unsigned int p_nxt = 0u;
        if (r + 1 < R_SP && w + 1 < KN) {
            int bn = __shfl(off_l, r + 1, 64), en = __shfl(off_l, r + 2, 64);
            int nn = en - bn;
            if (nn > 64) nn = 64;
            if (lane < nn) p_nxt = __builtin_nontemporal_load(&cmeta[bn + lane]);
        }
        // decode current row's prefetched meta
        int n_e = end - beg;
        if (n_e > 64) n_e = 64;
        int   c_l = k * N_;              // pad col (valid after base adjust)
        float v_l = 0.0f;
        if (lane < n_e) decode_meta(p_cur, c_l, v_l);
        // decoded col' = k*N + col; recover shared-X indexing by base adjust
        const ushort4* X4m = X4 - (size_t)k * N_ * (FEAT_ / 4);
        float4 acc = {0.f, 0.f, 0.f, 0.f};
        chunk_accum<4>(c_l, v_l, n_e, X4m, sub, q, acc);
        if (end - beg > 64)              // astronomically rare
            tail_accum<4>(cmeta, X4m, beg + 64, end, lane, sub, q, k * N_, acc);
        p_cur = p_nxt;
        butterfly4(acc);                 // all lanes hold row sums
        if (sub == 0) {
            int idx4 = (k * N_ + n) * (FEAT_ / 4) + q;
            float thr = c_nu[k] * d[n];
            float4 y;
            if (FIRST) {
                y = make_float4(0.f, 0.f, 0.f, 0.f);
            } else {
                ushort4 vp = V4[idx4];   // v_{t-1}
                y.x = acc.x + bf2f(vp.x); y.y = acc.y + bf2f(vp.y);
                y.z = acc.z + bf2f(vp.z); y.w = acc.w + bf2f(vp.w);
            }
            ushort4 o;
            o.x = f2bf(y.x - softf(acc.x + y.x, thr));
            o.y = f2bf(y.y - softf(acc.y + y.y, thr));
            o.z = f2bf(y.z - softf(acc.z + y.z, thr));
            o.w = f2bf(y.w - softf(acc.w + y.w, thr));
            V4[idx4] = o;                // v_t
        }
    }
}

// wave per R_WT nodes: node n's edges over ALL k are one flat contiguous
// segment [offs[4n], offs[4n+4]) gathering V_bf[col'] directly.
// Segments are mean 64 +- 8 edges -> prefetch TWO 64-edge meta chunks for
// node r+1 during node r; chunks beyond 128 via tail_accum (negligible).
// U = (dm*F - acc)/(dm+1); fp32 U stored ONLY when LAST (d_out is graded
// once); bf16 copy always (it feeds the next spmm's gathers).
template <bool LAST>
__global__ __launch_bounds__(BLK) void wtv_u_kernel(
    const int* __restrict__ offs, const unsigned int* __restrict__ cmeta,
    const unsigned short* __restrict__ V_bf,
    const float* __restrict__ F, const float* __restrict__ dm,
    float* __restrict__ U, unsigned short* __restrict__ U_bf) {
    int wave = (blockIdx.x * BLK + threadIdx.x) >> 6;
    int lane = threadIdx.x & 63;
    int sub  = lane >> 4, q = lane & 15;
    int base = wave * R_WT;
    if (base >= N_) return;
    int off_l = 0;
    if (lane <= K_ * R_WT) {             // 17 offsets
        int i = K_ * base + lane;
        if (i > KN) i = KN;
        off_l = offs[i];
    }
    const ushort4* V4 = (const ushort4*)V_bf;

    // prefetch node 0 meta (two chunks)
    unsigned int p0 = 0u, p1 = 0u;
    {
        int b0 = __shfl(off_l, 0, 64), e0 = __shfl(off_l, K_, 64);
        int nn = e0 - b0;
        if (lane < nn) p0 = __builtin_nontemporal_load(&cmeta[b0 + lane]);
        if (64 + lane < nn) p1 = __builtin_nontemporal_load(&cmeta[b0 + 64 + lane]);
    }
    for (int r = 0; r < R_WT; ++r) {
        int n = base + r;
        if (n >= N_) break;
        int beg = __shfl(off_l, K_ * r, 64);
        int end = __shfl(off_l, K_ * r + K_, 64);
        // issue next node's meta loads (overlap this node's gathers)
        unsigned int q0 = 0u, q1 = 0u;
        if (r + 1 < R_WT && n + 1 < N_) {
            int bn = __shfl(off_l, K_ * r + K_, 64);
            int en = __shfl(off_l, K_ * r + 2 * K_, 64);
            int nn = en - bn;
            if (lane < nn) q0 = __builtin_nontemporal_load(&cmeta[bn + lane]);
            if (64 + lane < nn) q1 = __builtin_nontemporal_load(&cmeta[bn + 64 + lane]);
        }
        int ne = end - beg;
        float4 acc = {0.f, 0.f, 0.f, 0.f};
        // chunk 0
        {
            int n0 = ne > 64 ? 64 : ne;
            int   c_l = 0;
            float v_l = 0.0f;
            if (lane < n0) decode_meta(p0, c_l, v_l);
            chunk_accum<8>(c_l, v_l, n0, V4, sub, q, acc);
        }
        // chunk 1
        if (ne > 64) {
            int n1 = ne - 64;
            if (n1 > 64) n1 = 64;
            int   c_l = 0;
            float v_l = 0.0f;
            if (lane < n1) decode_meta(p1, c_l, v_l);
            chunk_accum<2>(c_l, v_l, n1, V4, sub, q, acc);
        }
        if (ne > 128)                     // negligible tail
            tail_accum<2>(cmeta, V4, beg + 128, end, lane, sub, q, 0, acc);
        p0 = q0; p1 = q1;
        butterfly4(acc);
        if (sub == 0) {
            int idx4 = n * (FEAT_ / 4) + q;
            float dmv = dm[n];
            float r2 = 1.0f / (dmv + 1.0f);
            float4 f = ((const float4*)F)[idx4];
            float4 o;
            o.x = (dmv * f.x - acc.x) * r2; o.y = (dmv * f.y - acc.y) * r2;
            o.z = (dmv * f.z - acc.z) * r2; o.w = (dmv * f.w - acc.w) * r2;
            if (LAST) ((float4*)U)[idx4] = o;
            ushort4 ob;
            ob.x = f2bf(o.x); ob.y = f2bf(o.y);
            ob.z = f2bf(o.z); ob.w = f2bf(o.w);
            ((ushort4*)U_bf)[idx4] = ob;
        }
    }
}

extern "C" void kernel_launch(void* const* d_in, const int* in_sizes, int n_in,
                              void* d_out, int out_size, void* d_ws, size_t ws_size,
                              hipStream_t stream) {
    const float* F      = (const float*)d_in[0];
    const int*   w_rows = (const int*)d_in[1];
    const int*   w_cols = (const int*)d_in[2];
    const float* w_vals = (const float*)d_in[3];
    const float* d      = (const float*)d_in[4];
    const float* mask   = (const float*)d_in[5];
    float* U = (float*)d_out;

    // workspace layout (~27 MB)
    unsigned int* cmeta  = (unsigned int*)d_ws;               // NEDGE u32
    unsigned short* V_bf = (unsigned short*)(cmeta + NEDGE);  // KN*FEAT us
    unsigned short* U_bf = V_bf + (size_t)KN * FEAT_;         // NF us
    unsigned short* F_bf = U_bf + NF;                         // NF us
    float* dm     = (float*)(F_bf + NF);                      // N
    int*   cnt8   = (int*)(dm + N_);                          // NCPY*KN
    int*   loc    = cnt8 + NCPY * KN;                         // KN
    int*   bsum   = loc + KN;                                 // pad 512
    int*   offs   = bsum + 512;                               // KN+1
    int*   cursor = offs + KN + 1;                            // KN
    unsigned short* rows16 = (unsigned short*)(cursor + KN);  // NEDGE u16

    const int gEdge = NEDGE / BLK;                // 5000
    const int gNF4  = (NF / 4) / BLK;             // 1250

    // ---- CSR build + precompute ----
    hipMemsetAsync(cnt8, 0, (size_t)NCPY * KN * 4, stream);
    precompute_kernel<<<gNF4, BLK, 0, stream>>>(F, d, mask, dm, F_bf);
    hist_kernel<<<gEdge, BLK, 0, stream>>>(w_rows, cnt8, rows16);
    scan1_kernel<<<NSB, 256, 0, stream>>>(cnt8, loc, bsum);
    scan2_kernel<<<1, 512, 0, stream>>>(bsum);
    scan3_kernel<<<NSB, 256, 0, stream>>>(loc, bsum, offs, cursor);
    scatter_kernel<<<NVB * NXCD, BLK, 0, stream>>>(rows16, w_cols, w_vals,
                                                   cursor, cmeta);

    // ---- iterations ----
    spmm_fused_kernel<true><<<NB_SP, BLK, 0, stream>>>(offs, cmeta, F_bf, d, V_bf);
    for (int it = 0; it < NITER; ++it) {
        if (it < NITER - 1) {
            wtv_u_kernel<false><<<NB_WT, BLK, 0, stream>>>(offs, cmeta, V_bf,
                                                           F, dm, U, U_bf);
            spmm_fused_kernel<false><<<NB_SP, BLK, 0, stream>>>(offs, cmeta,
                                                                U_bf, d, V_bf);
        } else {
            wtv_u_kernel<true><<<NB_WT, BLK, 0, stream>>>(offs, cmeta, V_bf,
                                                          F, dm, U, U_bf);
        }
    }
}

// Round 5
// 945.892 us; speedup vs baseline: 1.0077x; 1.0077x over previous
//
#include <hip/hip_runtime.h>

// NodeDenoisingADMM: N=20000, FEAT=64, K=4, NNZ=320000, NU=2.0, GAMMA=1.0, J=3
// 14 scan iterations, output = final U (N,FEAT) fp32.
//
// State reduction (GAMMA=1): carried state is v alone.
//   S_t = W_k @ U_t ; Y_t = S_t + v_{t-1} ; Z_t = soft(S_t + Y_t, nu_k d)
//   v_t = Y_t - Z_t ; U_{t+1} = (dm*F - sum_k W_k v_k)/(dm+1), dm = d*mask^2
//
// Node-major CSR: rowid = n*K + k. Edge meta packed in 4 B:
//   [31] sign | [30:26] exp5 (bias 96, 0 => value 0) | [25:17] mant9 (RNE)
//   | [16:15] k | [14:0] col       (rel err 2^-11 < bf16 operand err)
// Scatter is XCD-FILTERED (8 buckets by row/2500, block handles bucket
// blockIdx%8) so cursor/cmeta dirty lines live in ONE XCD's L2.
// HISTORY: R1 k-phasing wtv REGRESSED (4x per-segment overhead > L2 gain).
// R2 meta software pipeline: +27 us (keep). R3 NT loads REGRESSED -46 us
// (NT = forced L2 miss; scatter and meta chains are latency-bound, and
// cmeta was L2-resident across dispatches) -> all NT reverted; LAST-only
// fp32 U store kept (pure write elimination, 13 x 5.12 MB).
// R4: GATHER software pipeline — decode next row's (prefetched) meta and
// ISSUE its X-gather batch before the current row's butterfly+store, so
// gather latency (~200-600cy) hides under compute. spmm prefetches batch0
// only (4 slots; keeps VGPR low for its 8-waves/SIMD grid); wtv prefetches
// 16 slots (grid occupancy-capped ~5 waves/SIMD, VGPR headroom free).
// Batch grouping/order preserved exactly -> bit-identical output.
// (R4 bench was an infra failure - container died twice, no verdict;
// resubmitted unchanged.)

constexpr int N_    = 20000;
constexpr int FEAT_ = 64;
constexpr int K_    = 4;
constexpr int NNZ_  = 320000;
constexpr int NF    = N_ * FEAT_;     // 1,280,000
constexpr int KN    = K_ * N_;        // 80,000 CSR rows
constexpr int NEDGE = K_ * NNZ_;      // 1,280,000
constexpr int NITER = 14;
constexpr int BLK   = 256;
constexpr int NSB   = (KN + 255) / 256;  // 313 scan blocks
constexpr int NCPY  = 8;                 // hist privatization copies
constexpr int NXCD  = 8;
constexpr int EPV   = 2048;              // edges per virtual scatter block
constexpr int NVB   = NEDGE / EPV;       // 625 virtual blocks

constexpr int R_SP  = 10;                          // CSR rows/wave, spmm
constexpr int NB_SP = ((KN + R_SP - 1) / R_SP + 3) / 4;   // 2000 blocks
constexpr int R_WT  = 4;                           // nodes/wave, wtv
constexpr int NB_WT = ((N_ + R_WT - 1) / R_WT + 3) / 4;   // 1250 blocks

__constant__ float c_nu[4] = {0.0f, 2.0f, 0.5f, 0.125f};

__device__ __forceinline__ float softf(float x, float t) {
    float a = fabsf(x) - t;
    a = a > 0.0f ? a : 0.0f;
    return copysignf(a, x);
}

__device__ __forceinline__ float bf2f(unsigned short u) {
    union { unsigned int i; float f; } x;
    x.i = ((unsigned int)u) << 16;
    return x.f;
}
__device__ __forceinline__ unsigned short f2bf(float f) {   // RNE
    union { float f; unsigned int i; } x;
    x.f = f;
    unsigned int r = x.i + 0x7FFFu + ((x.i >> 16) & 1u);
    return (unsigned short)(r >> 16);
}

__device__ __forceinline__ void decode_meta(unsigned int p, int& c, float& v) {
    c = (int)((p >> 15) & 3u) * N_ + (int)(p & 0x7FFFu);
    unsigned int e5 = (p >> 26) & 0x1Fu;
    unsigned int bits = (p & 0x80000000u) | ((e5 + 96u) << 23) |
                        (((p >> 17) & 0x1FFu) << 14);
    v = (e5 == 0u) ? 0.0f : __uint_as_float(bits);
}

__device__ __forceinline__ void fma4(float4& acc, float v, const ushort4& x) {
    acc.x += v * bf2f(x.x);
    acc.y += v * bf2f(x.y);
    acc.z += v * bf2f(x.z);
    acc.w += v * bf2f(x.w);
}

// ---------------- CSR build + precompute ----------------

// dm[n] = d*mask^2 ; F_bf = bf16(F)
__global__ __launch_bounds__(BLK) void precompute_kernel(
    const float* __restrict__ F, const float* __restrict__ d,
    const float* __restrict__ mask, float* __restrict__ dm,
    unsigned short* __restrict__ F_bf) {
    int i = blockIdx.x * BLK + threadIdx.x;       // over NF/4
    if (i >= NF / 4) return;
    float4 f = ((const float4*)F)[i];
    ushort4 o;
    o.x = f2bf(f.x); o.y = f2bf(f.y); o.z = f2bf(f.z); o.w = f2bf(f.w);
    ((ushort4*)F_bf)[i] = o;
    if ((i & (FEAT_ / 4 - 1)) == 0) {
        int n = i / (FEAT_ / 4);
        dm[n] = d[n] * mask[n] * mask[n];
    }
}

// rowid = rows[e]*K + k ; privatized copies (blockIdx&7)
__global__ __launch_bounds__(BLK) void hist_kernel(
    const int* __restrict__ rows, int* __restrict__ cnt8) {
    int e = blockIdx.x * BLK + threadIdx.x;
    if (e >= NEDGE) return;
    int k = e / NNZ_;
    int copy = blockIdx.x & (NCPY - 1);
    atomicAdd(&cnt8[copy * KN + rows[e] * K_ + k], 1);
}

// block-local exclusive scan over summed copies + block sums
__global__ __launch_bounds__(256) void scan1_kernel(
    const int* __restrict__ cnt8, int* __restrict__ loc,
    int* __restrict__ bsum) {
    int i = blockIdx.x * 256 + threadIdx.x;
    int x = 0;
    if (i < KN) {
        #pragma unroll
        for (int c = 0; c < NCPY; ++c) x += cnt8[c * KN + i];
    }
    int lane = threadIdx.x & 63, wid = threadIdx.x >> 6;
    int v = x;
    #pragma unroll
    for (int off = 1; off < 64; off <<= 1) {
        int t = __shfl_up(v, off, 64);
        if (lane >= off) v += t;
    }
    __shared__ int ws[4];
    if (lane == 63) ws[wid] = v;
    __syncthreads();
    int add = 0;
    for (int u = 0; u < wid; ++u) add += ws[u];
    v += add;
    if (i < KN) loc[i] = v - x;
    if (threadIdx.x == 255) bsum[blockIdx.x] = v;
}

__global__ __launch_bounds__(512) void scan2_kernel(int* __restrict__ bsum) {
    int tid = threadIdx.x;
    int x = (tid < NSB) ? bsum[tid] : 0;
    int lane = tid & 63, wid = tid >> 6;
    int v = x;
    #pragma unroll
    for (int off = 1; off < 64; off <<= 1) {
        int t = __shfl_up(v, off, 64);
        if (lane >= off) v += t;
    }
    __shared__ int ws[8];
    if (lane == 63) ws[wid] = v;
    __syncthreads();
    int add = 0;
    for (int u = 0; u < wid; ++u) add += ws[u];
    v += add;
    if (tid < NSB) bsum[tid] = v - x;
}

__global__ __launch_bounds__(256) void scan3_kernel(
    const int* __restrict__ loc, const int* __restrict__ bsum,
    int* __restrict__ offs, int* __restrict__ cursor) {
    int i = blockIdx.x * 256 + threadIdx.x;
    if (i < KN) {
        int v = loc[i] + bsum[blockIdx.x];
        offs[i] = v;
        cursor[i] = v;
    }
    if (i == 0) offs[KN] = NEDGE;
}

// XCD-filtered scatter (R2 form — NT variant regressed, see header).
__global__ __launch_bounds__(BLK) void scatter_kernel(
    const int* __restrict__ rows, const int* __restrict__ cols,
    const float* __restrict__ vals, int* __restrict__ cursor,
    unsigned int* __restrict__ cmeta) {
    int xcd = blockIdx.x & (NXCD - 1);
    int vb  = blockIdx.x >> 3;
    int ebase = vb * EPV;
    #pragma unroll
    for (int i = 0; i < EPV / BLK; ++i) {
        int e = ebase + i * BLK + threadIdx.x;
        int row = rows[e];
        if (row / (N_ / NXCD) != xcd) continue;
        int k = e / NNZ_;
        unsigned int b  = __float_as_uint(vals[e]);
        unsigned int rb = b + 0x1FFFu + ((b >> 14) & 1u);  // RNE to 9 mant
        int exp8 = (int)((rb >> 23) & 0xFF);
        unsigned int pk = 0u;
        if (exp8 > 96)                                     // else flush to 0
            pk = (b & 0x80000000u) | ((unsigned int)(exp8 - 96) << 26) |
                 (((rb >> 14) & 0x1FFu) << 17);
        pk |= ((unsigned int)k << 15) | (unsigned int)cols[e];
        int pos = atomicAdd(&cursor[row * K_ + k], 1);
        cmeta[pos] = pk;
    }
}

// ---------------- iteration kernels ----------------

// load+FMA groups of BATCH, iterations [it_start, ceil(n/4)) over a decoded
// chunk (c_l, v_l; lanes >= n hold (pad, 0)). n <= 64 guaranteed -> j <= 63.
template <int BATCH>
__device__ __forceinline__ void accum_from(
    int c_l, float v_l, int n, int it_start, const ushort4* __restrict__ Xb,
    int sub, int q, float4& acc) {
    int iters = (n + 3) >> 2;
    for (int it0 = it_start; it0 < iters; it0 += BATCH) {
        float   vv[BATCH];
        ushort4 xx[BATCH];
        #pragma unroll
        for (int u = 0; u < BATCH; ++u) {
            int j = 4 * (it0 + u) + sub;
            int c = __shfl(c_l, j, 64);
            vv[u] = __shfl(v_l, j, 64);
            xx[u] = Xb[(size_t)c * (FEAT_ / 4) + q];
        }
        #pragma unroll
        for (int u = 0; u < BATCH; ++u) fma4(acc, vv[u], xx[u]);
    }
}

// Fallback: load+decode+accumulate windows [beg,end). Only for the
// astronomically rare chunks beyond the pipelined ones.
template <int BATCH>
__device__ __forceinline__ void tail_accum(
    const unsigned int* __restrict__ cmeta, const ushort4* __restrict__ Xb,
    int beg, int end, int lane, int sub, int q, int padc, float4& acc) {
    for (int eb = beg; eb < end; eb += 64) {
        int n = end - eb;
        if (n > 64) n = 64;
        int   c_l = padc;
        float v_l = 0.0f;
        if (lane < n) {
            unsigned int p = cmeta[eb + lane];
            decode_meta(p, c_l, v_l);
        }
        accum_from<BATCH>(c_l, v_l, n, 0, Xb, sub, q, acc);
    }
}

__device__ __forceinline__ void butterfly4(float4& a) {
    #pragma unroll
    for (int m = 16; m <= 32; m <<= 1) {
        a.x += __shfl_xor(a.x, m, 64);
        a.y += __shfl_xor(a.y, m, 64);
        a.z += __shfl_xor(a.z, m, 64);
        a.w += __shfl_xor(a.w, m, 64);
    }
}

// wave per R_SP contiguous CSR rows (rowid = n*K+k); acc = (W_k @ X)[n];
// fused v-update into bf16 V_bf (layout [k][n]). FIRST: Y=0, X=F_bf.
// Pipeline (depth 1): at loop top, row r's meta is DECODED and its first
// gather batch (4 slots = 16 edges) is IN FLIGHT; row r+1's meta is in
// flight. Iteration: consume batch0 -> inline remainder (rows >16 edges)
// -> decode r+1 meta + issue r+1 batch0 -> prefetch r+2 meta -> butterfly
// + store (overlapping r+1's gathers).
template <bool FIRST>
__global__ __launch_bounds__(BLK) void spmm_fused_kernel(
    const int* __restrict__ offs, const unsigned int* __restrict__ cmeta,
    const unsigned short* __restrict__ Xb,
    const float* __restrict__ d, unsigned short* __restrict__ V_bf) {
    int wave = (blockIdx.x * BLK + threadIdx.x) >> 6;
    int lane = threadIdx.x & 63;
    int sub  = lane >> 4, q = lane & 15;
    int base = wave * R_SP;
    if (base >= KN) return;
    int off_l = 0;
    if (lane <= R_SP) {
        int i = base + lane;
        if (i > KN) i = KN;
        off_l = offs[i];
    }
    const ushort4* X4 = (const ushort4*)Xb;
    ushort4* V4 = (ushort4*)V_bf;

    // pipeline state: decoded meta + batch0 gathers for row "cur"
    int   cC = 0; float vC = 0.0f; int nC = 0;
    ushort4 xx[4]; float vv[4];
    unsigned int p_nxt = 0u;

    // prologue: row base
    {
        int b0 = __shfl(off_l, 0, 64), e0 = __shfl(off_l, 1, 64);
        nC = e0 - b0; if (nC > 64) nC = 64;
        int k0 = base & (K_ - 1);
        unsigned int p = 0u;
        if (lane < nC) p = cmeta[b0 + lane];
        cC = k0 * N_; vC = 0.0f;
        if (lane < nC) decode_meta(p, cC, vC);
        const ushort4* Xm = X4 - (size_t)k0 * N_ * (FEAT_ / 4);
        #pragma unroll
        for (int u = 0; u < 4; ++u) {
            int j = 4 * u + sub;
            int c = __shfl(cC, j, 64);
            vv[u] = __shfl(vC, j, 64);
            xx[u] = Xm[(size_t)c * (FEAT_ / 4) + q];
        }
        if (base + 1 < KN) {
            int b1 = e0, e1 = __shfl(off_l, 2, 64);
            int nn = e1 - b1; if (nn > 64) nn = 64;
            if (lane < nn) p_nxt = cmeta[b1 + lane];
        }
    }

    for (int r = 0; r < R_SP; ++r) {
        int w = base + r;
        if (w >= KN) break;
        int k = w & (K_ - 1);
        int n = w >> 2;
        int beg = __shfl(off_l, r, 64);
        int end = __shfl(off_l, r + 1, 64);
        int n_e = nC;
        const ushort4* Xm = X4 - (size_t)k * N_ * (FEAT_ / 4);
        float4 acc = {0.f, 0.f, 0.f, 0.f};
        // consume prefetched batch0 (loads had the previous row to land)
        #pragma unroll
        for (int u = 0; u < 4; ++u) fma4(acc, vv[u], xx[u]);
        // inline remainder (rows >16 edges; same grouping as before)
        if (n_e > 16)
            accum_from<4>(cC, vC, n_e, 4, Xm, sub, q, acc);
        if (end - beg > 64)              // astronomically rare
            tail_accum<4>(cmeta, Xm, beg + 64, end, lane, sub, q, k * N_, acc);
        // decode + issue NEXT row's batch0 (flies during butterfly/store)
        if (r + 1 < R_SP && w + 1 < KN) {
            int bn = end, en = __shfl(off_l, r + 2, 64);
            nC = en - bn; if (nC > 64) nC = 64;
            int kn = (w + 1) & (K_ - 1);
            cC = kn * N_; vC = 0.0f;
            if (lane < nC) decode_meta(p_nxt, cC, vC);
            const ushort4* Xn = X4 - (size_t)kn * N_ * (FEAT_ / 4);
            #pragma unroll
            for (int u = 0; u < 4; ++u) {
                int j = 4 * u + sub;
                int c = __shfl(cC, j, 64);
                vv[u] = __shfl(vC, j, 64);
                xx[u] = Xn[(size_t)c * (FEAT_ / 4) + q];
            }
            p_nxt = 0u;
            if (r + 2 < R_SP && w + 2 < KN) {
                int b2 = en, e2 = __shfl(off_l, r + 3, 64);
                int nn = e2 - b2; if (nn > 64) nn = 64;
                if (lane < nn) p_nxt = cmeta[b2 + lane];
            }
        }
        butterfly4(acc);                 // all lanes hold row sums
        if (sub == 0) {
            int idx4 = (k * N_ + n) * (FEAT_ / 4) + q;
            float thr = c_nu[k] * d[n];
            float4 y;
            if (FIRST) {
                y = make_float4(0.f, 0.f, 0.f, 0.f);
            } else {
                ushort4 vp = V4[idx4];   // v_{t-1}
                y.x = acc.x + bf2f(vp.x); y.y = acc.y + bf2f(vp.y);
                y.z = acc.z + bf2f(vp.z); y.w = acc.w + bf2f(vp.w);
            }
            ushort4 o;
            o.x = f2bf(y.x - softf(acc.x + y.x, thr));
            o.y = f2bf(y.y - softf(acc.y + y.y, thr));
            o.z = f2bf(y.z - softf(acc.z + y.z, thr));
            o.w = f2bf(y.w - softf(acc.w + y.w, thr));
            V4[idx4] = o;                // v_t
        }
    }
}

// wave per R_WT nodes: node n's edges over ALL k are one flat contiguous
// segment [offs[4n], offs[4n+4]) gathering V_bf[col'] directly.
// Pipeline (depth 1): at loop top, node r's TWO meta chunks are decoded and
// its first 16 gather slots (64 edges; second 8 conditional on >32) are in
// flight; node r+1's meta is in flight. Grid is occupancy-capped (~5
// waves/SIMD) so the extra ~50 VGPR of pipeline state is free.
// U = (dm*F - acc)/(dm+1); fp32 U stored ONLY when LAST; bf16 copy always.
template <bool LAST>
__global__ __launch_bounds__(BLK) void wtv_u_kernel(
    const int* __restrict__ offs, const unsigned int* __restrict__ cmeta,
    const unsigned short* __restrict__ V_bf,
    const float* __restrict__ F, const float* __restrict__ dm,
    float* __restrict__ U, unsigned short* __restrict__ U_bf) {
    int wave = (blockIdx.x * BLK + threadIdx.x) >> 6;
    int lane = threadIdx.x & 63;
    int sub  = lane >> 4, q = lane & 15;
    int base = wave * R_WT;
    if (base >= N_) return;
    int off_l = 0;
    if (lane <= K_ * R_WT) {             // 17 offsets
        int i = K_ * base + lane;
        if (i > KN) i = KN;
        off_l = offs[i];
    }
    const ushort4* V4 = (const ushort4*)V_bf;

    // pipeline state for node "cur": decoded chunk0 (c0,v0) + chunk1 (c1,v1),
    // segment length neC, 16 gather slots; meta for node cur+1 in flight.
    int c0 = 0, c1 = 0; float v0 = 0.0f, v1 = 0.0f; int neC = 0;
    ushort4 xx[16]; float vv[16];
    unsigned int q0 = 0u, q1 = 0u;

    // prologue: node base
    {
        int b0 = __shfl(off_l, 0, 64), e0 = __shfl(off_l, K_, 64);
        neC = e0 - b0;
        unsigned int p0 = 0u, p1 = 0u;
        if (lane < neC) p0 = cmeta[b0 + lane];
        if (64 + lane < neC) p1 = cmeta[b0 + 64 + lane];
        int n0 = neC > 64 ? 64 : neC;
        if (lane < n0) decode_meta(p0, c0, v0);
        if (neC > 64) {
            int n1 = neC - 64; if (n1 > 64) n1 = 64;
            if (lane < n1) decode_meta(p1, c1, v1);
        }
        #pragma unroll
        for (int u = 0; u < 8; ++u) {
            int j = 4 * u + sub;
            int c = __shfl(c0, j, 64);
            vv[u] = __shfl(v0, j, 64);
            xx[u] = V4[(size_t)c * (FEAT_ / 4) + q];
        }
        if (n0 > 32) {
            #pragma unroll
            for (int u = 8; u < 16; ++u) {
                int j = 4 * u + sub;
                int c = __shfl(c0, j, 64);
                vv[u] = __shfl(v0, j, 64);
                xx[u] = V4[(size_t)c * (FEAT_ / 4) + q];
            }
        }
        if (base + 1 < N_) {
            int bn = e0, en = __shfl(off_l, 2 * K_, 64);
            int nn = en - bn;
            if (lane < nn) q0 = cmeta[bn + lane];
            if (64 + lane < nn) q1 = cmeta[bn + 64 + lane];
        }
    }

    for (int r = 0; r < R_WT; ++r) {
        int n = base + r;
        if (n >= N_) break;
        int beg = __shfl(off_l, K_ * r, 64);
        int end = __shfl(off_l, K_ * r + K_, 64);
        int ne = neC;
        int n0 = ne > 64 ? 64 : ne;
        float4 acc = {0.f, 0.f, 0.f, 0.f};
        // chunk0 prefetched: group {0..7} always, {8..15} if >32 edges
        #pragma unroll
        for (int u = 0; u < 8; ++u) fma4(acc, vv[u], xx[u]);
        if (n0 > 32) {
            #pragma unroll
            for (int u = 8; u < 16; ++u) fma4(acc, vv[u], xx[u]);
        }
        // chunk1 inline (same BATCH=2 grouping as before)
        if (ne > 64) {
            int n1 = ne - 64; if (n1 > 64) n1 = 64;
            accum_from<2>(c1, v1, n1, 0, V4, sub, q, acc);
        }
        if (ne > 128)                     // negligible tail
            tail_accum<2>(cmeta, V4, beg + 128, end, lane, sub, q, 0, acc);
        // decode + issue NEXT node's chunk0 gathers (fly during butterfly)
        if (r + 1 < R_WT && n + 1 < N_) {
            int bn = end, en = __shfl(off_l, K_ * r + 2 * K_, 64);
            neC = en - bn;
            int n0n = neC > 64 ? 64 : neC;
            c0 = 0; v0 = 0.0f; c1 = 0; v1 = 0.0f;
            if (lane < n0n) decode_meta(q0, c0, v0);
            if (neC > 64) {
                int n1n = neC - 64; if (n1n > 64) n1n = 64;
                if (lane < n1n) decode_meta(q1, c1, v1);
            }
            #pragma unroll
            for (int u = 0; u < 8; ++u) {
                int j = 4 * u + sub;
                int c = __shfl(c0, j, 64);
                vv[u] = __shfl(v0, j, 64);
                xx[u] = V4[(size_t)c * (FEAT_ / 4) + q];
            }
            if (n0n > 32) {
                #pragma unroll
                for (int u = 8; u < 16; ++u) {
                    int j = 4 * u + sub;
                    int c = __shfl(c0, j, 64);
                    vv[u] = __shfl(v0, j, 64);
                    xx[u] = V4[(size_t)c * (FEAT_ / 4) + q];
                }
            }
            // prefetch meta for node r+2
            q0 = 0u; q1 = 0u;
            if (r + 2 < R_WT && n + 2 < N_) {
                int b2 = en, e2 = __shfl(off_l, K_ * r + 3 * K_, 64);
                int nn = e2 - b2;
                if (lane < nn) q0 = cmeta[b2 + lane];
                if (64 + lane < nn) q1 = cmeta[b2 + 64 + lane];
            }
        }
        butterfly4(acc);
        if (sub == 0) {
            int idx4 = n * (FEAT_ / 4) + q;
            float dmv = dm[n];
            float r2 = 1.0f / (dmv + 1.0f);
            float4 f = ((const float4*)F)[idx4];
            float4 o;
            o.x = (dmv * f.x - acc.x) * r2; o.y = (dmv * f.y - acc.y) * r2;
            o.z = (dmv * f.z - acc.z) * r2; o.w = (dmv * f.w - acc.w) * r2;
            if (LAST) ((float4*)U)[idx4] = o;
            ushort4 ob;
            ob.x = f2bf(o.x); ob.y = f2bf(o.y);
            ob.z = f2bf(o.z); ob.w = f2bf(o.w);
            ((ushort4*)U_bf)[idx4] = ob;
        }
    }
}

extern "C" void kernel_launch(void* const* d_in, const int* in_sizes, int n_in,
                              void* d_out, int out_size, void* d_ws, size_t ws_size,
                              hipStream_t stream) {
    const float* F      = (const float*)d_in[0];
    const int*   w_rows = (const int*)d_in[1];
    const int*   w_cols = (const int*)d_in[2];
    const float* w_vals = (const float*)d_in[3];
    const float* d      = (const float*)d_in[4];
    const float* mask   = (const float*)d_in[5];
    float* U = (float*)d_out;

    // workspace layout (~29 MB)
    unsigned int* cmeta  = (unsigned int*)d_ws;               // NEDGE u32
    unsigned short* V_bf = (unsigned short*)(cmeta + NEDGE);  // KN*FEAT us
    unsigned short* U_bf = V_bf + (size_t)KN * FEAT_;         // NF us
    unsigned short* F_bf = U_bf + NF;                         // NF us
    float* dm     = (float*)(F_bf + NF);                      // N
    int*   cnt8   = (int*)(dm + N_);                          // NCPY*KN
    int*   loc    = cnt8 + NCPY * KN;                         // KN
    int*   bsum   = loc + KN;                                 // pad 512
    int*   offs   = bsum + 512;                               // KN+1
    int*   cursor = offs + KN + 1;                            // KN

    const int gEdge = NEDGE / BLK;                // 5000
    const int gNF4  = (NF / 4) / BLK;             // 1250

    // ---- CSR build + precompute ----
    hipMemsetAsync(cnt8, 0, (size_t)NCPY * KN * 4, stream);
    precompute_kernel<<<gNF4, BLK, 0, stream>>>(F, d, mask, dm, F_bf);
    hist_kernel<<<gEdge, BLK, 0, stream>>>(w_rows, cnt8);
    scan1_kernel<<<NSB, 256, 0, stream>>>(cnt8, loc, bsum);
    scan2_kernel<<<1, 512, 0, stream>>>(bsum);
    scan3_kernel<<<NSB, 256, 0, stream>>>(loc, bsum, offs, cursor);
    scatter_kernel<<<NVB * NXCD, BLK, 0, stream>>>(w_rows, w_cols, w_vals,
                                                   cursor, cmeta);

    // ---- iterations ----
    spmm_fused_kernel<true><<<NB_SP, BLK, 0, stream>>>(offs, cmeta, F_bf, d, V_bf);
    for (int it = 0; it < NITER; ++it) {
        if (it < NITER - 1) {
            wtv_u_kernel<false><<<NB_WT, BLK, 0, stream>>>(offs, cmeta, V_bf,
                                                           F, dm, U, U_bf);
            spmm_fused_kernel<false><<<NB_SP, BLK, 0, stream>>>(offs, cmeta,
                                                                U_bf, d, V_bf);
        } else {
            wtv_u_kernel<true><<<NB_WT, BLK, 0, stream>>>(offs, cmeta, V_bf,
                                                          F, dm, U, U_bf);
        }
    }
}

// Round 6
// 911.641 us; speedup vs baseline: 1.0455x; 1.0376x over previous
//
#include <hip/hip_runtime.h>

// NodeDenoisingADMM: N=20000, FEAT=64, K=4, NNZ=320000, NU=2.0, GAMMA=1.0, J=3
// 14 scan iterations, output = final U (N,FEAT) fp32.
//
// State reduction (GAMMA=1): carried state is v alone.
//   S_t = W_k @ U_t ; Y_t = S_t + v_{t-1} ; Z_t = soft(S_t + Y_t, nu_k d)
//   v_t = Y_t - Z_t ; U_{t+1} = (dm*F - sum_k W_k v_k)/(dm+1), dm = d*mask^2
//
// Node-major CSR: rowid = n*K + k. Edge meta packed in 4 B:
//   [31] sign | [30:26] exp5 (bias 96, 0 => value 0) | [25:17] mant9 (RNE)
//   | [16:15] k | [14:0] col       (rel err 2^-11 < bf16 operand err)
// Scatter is XCD-FILTERED (8 buckets by row/2500, block handles bucket
// blockIdx%8) so cursor/cmeta dirty lines live in ONE XCD's L2.
// HISTORY: R1 k-phasing wtv REGRESSED (4x per-segment overhead > L2 gain).
// R2 meta software pipeline: WIN, keep (meta for row r+1 in flight during
// row r's gathers). R3 NT loads REGRESSED -46 us (NT = forced L2 miss on
// latency-bound chains). R4/R5 gather pipeline REGRESSED +49 us vs R2
// (pipeline state +80 VGPR -> occupancy step-down; TLP is the hiding
// mechanism here, don't trade it for ILP) -> reverted to R2 inner loops.
// KEPT from R3/R4: LAST-only fp32 U store (pure write elim, 13x5.12 MB).
// R6: scatter MLP phases — split the 8-edge loop into phases (load all
// rows / load all cols+vals / pack / issue all 8 atomics / write all),
// so 8 independent cursor-atomic round-trips overlap instead of
// serializing one per iteration. Scatter is latency-bound (25% HBM).

constexpr int N_    = 20000;
constexpr int FEAT_ = 64;
constexpr int K_    = 4;
constexpr int NNZ_  = 320000;
constexpr int NF    = N_ * FEAT_;     // 1,280,000
constexpr int KN    = K_ * N_;        // 80,000 CSR rows
constexpr int NEDGE = K_ * NNZ_;      // 1,280,000
constexpr int NITER = 14;
constexpr int BLK   = 256;
constexpr int NSB   = (KN + 255) / 256;  // 313 scan blocks
constexpr int NCPY  = 8;                 // hist privatization copies
constexpr int NXCD  = 8;
constexpr int EPV   = 2048;              // edges per virtual scatter block
constexpr int NVB   = NEDGE / EPV;       // 625 virtual blocks

constexpr int R_SP  = 10;                          // CSR rows/wave, spmm
constexpr int NB_SP = ((KN + R_SP - 1) / R_SP + 3) / 4;   // 2000 blocks
constexpr int R_WT  = 4;                           // nodes/wave, wtv
constexpr int NB_WT = ((N_ + R_WT - 1) / R_WT + 3) / 4;   // 1250 blocks

__constant__ float c_nu[4] = {0.0f, 2.0f, 0.5f, 0.125f};

__device__ __forceinline__ float softf(float x, float t) {
    float a = fabsf(x) - t;
    a = a > 0.0f ? a : 0.0f;
    return copysignf(a, x);
}

__device__ __forceinline__ float bf2f(unsigned short u) {
    union { unsigned int i; float f; } x;
    x.i = ((unsigned int)u) << 16;
    return x.f;
}
__device__ __forceinline__ unsigned short f2bf(float f) {   // RNE
    union { float f; unsigned int i; } x;
    x.f = f;
    unsigned int r = x.i + 0x7FFFu + ((x.i >> 16) & 1u);
    return (unsigned short)(r >> 16);
}

__device__ __forceinline__ void decode_meta(unsigned int p, int& c, float& v) {
    c = (int)((p >> 15) & 3u) * N_ + (int)(p & 0x7FFFu);
    unsigned int e5 = (p >> 26) & 0x1Fu;
    unsigned int bits = (p & 0x80000000u) | ((e5 + 96u) << 23) |
                        (((p >> 17) & 0x1FFu) << 14);
    v = (e5 == 0u) ? 0.0f : __uint_as_float(bits);
}

// ---------------- CSR build + precompute ----------------

// dm[n] = d*mask^2 ; F_bf = bf16(F)
__global__ __launch_bounds__(BLK) void precompute_kernel(
    const float* __restrict__ F, const float* __restrict__ d,
    const float* __restrict__ mask, float* __restrict__ dm,
    unsigned short* __restrict__ F_bf) {
    int i = blockIdx.x * BLK + threadIdx.x;       // over NF/4
    if (i >= NF / 4) return;
    float4 f = ((const float4*)F)[i];
    ushort4 o;
    o.x = f2bf(f.x); o.y = f2bf(f.y); o.z = f2bf(f.z); o.w = f2bf(f.w);
    ((ushort4*)F_bf)[i] = o;
    if ((i & (FEAT_ / 4 - 1)) == 0) {
        int n = i / (FEAT_ / 4);
        dm[n] = d[n] * mask[n] * mask[n];
    }
}

// rowid = rows[e]*K + k ; privatized copies (blockIdx&7)
__global__ __launch_bounds__(BLK) void hist_kernel(
    const int* __restrict__ rows, int* __restrict__ cnt8) {
    int e = blockIdx.x * BLK + threadIdx.x;
    if (e >= NEDGE) return;
    int k = e / NNZ_;
    int copy = blockIdx.x & (NCPY - 1);
    atomicAdd(&cnt8[copy * KN + rows[e] * K_ + k], 1);
}

// block-local exclusive scan over summed copies + block sums
__global__ __launch_bounds__(256) void scan1_kernel(
    const int* __restrict__ cnt8, int* __restrict__ loc,
    int* __restrict__ bsum) {
    int i = blockIdx.x * 256 + threadIdx.x;
    int x = 0;
    if (i < KN) {
        #pragma unroll
        for (int c = 0; c < NCPY; ++c) x += cnt8[c * KN + i];
    }
    int lane = threadIdx.x & 63, wid = threadIdx.x >> 6;
    int v = x;
    #pragma unroll
    for (int off = 1; off < 64; off <<= 1) {
        int t = __shfl_up(v, off, 64);
        if (lane >= off) v += t;
    }
    __shared__ int ws[4];
    if (lane == 63) ws[wid] = v;
    __syncthreads();
    int add = 0;
    for (int u = 0; u < wid; ++u) add += ws[u];
    v += add;
    if (i < KN) loc[i] = v - x;
    if (threadIdx.x == 255) bsum[blockIdx.x] = v;
}

__global__ __launch_bounds__(512) void scan2_kernel(int* __restrict__ bsum) {
    int tid = threadIdx.x;
    int x = (tid < NSB) ? bsum[tid] : 0;
    int lane = tid & 63, wid = tid >> 6;
    int v = x;
    #pragma unroll
    for (int off = 1; off < 64; off <<= 1) {
        int t = __shfl_up(v, off, 64);
        if (lane >= off) v += t;
    }
    __shared__ int ws[8];
    if (lane == 63) ws[wid] = v;
    __syncthreads();
    int add = 0;
    for (int u = 0; u < wid; ++u) add += ws[u];
    v += add;
    if (tid < NSB) bsum[tid] = v - x;
}

__global__ __launch_bounds__(256) void scan3_kernel(
    const int* __restrict__ loc, const int* __restrict__ bsum,
    int* __restrict__ offs, int* __restrict__ cursor) {
    int i = blockIdx.x * 256 + threadIdx.x;
    if (i < KN) {
        int v = loc[i] + bsum[blockIdx.x];
        offs[i] = v;
        cursor[i] = v;
    }
    if (i == 0) offs[KN] = NEDGE;
}

// XCD-filtered scatter, MLP-PHASED (R6): all 8 edges' loads, then all
// packs, then all 8 atomics back-to-back (8 cursor round-trips overlap),
// then all cmeta writes. Latency-bound before (one serial
// atomic->wait->write chain per unrolled iteration).
__global__ __launch_bounds__(BLK) void scatter_kernel(
    const int* __restrict__ rows, const int* __restrict__ cols,
    const float* __restrict__ vals, int* __restrict__ cursor,
    unsigned int* __restrict__ cmeta) {
    constexpr int NI = EPV / BLK;        // 8
    int xcd = blockIdx.x & (NXCD - 1);
    int vb  = blockIdx.x >> 3;
    int e0  = vb * EPV + threadIdx.x;

    int row[NI];
    #pragma unroll
    for (int i = 0; i < NI; ++i) row[i] = rows[e0 + i * BLK];

    bool act[NI];
    int  col[NI];
    float val[NI];
    #pragma unroll
    for (int i = 0; i < NI; ++i) {
        act[i] = (row[i] / (N_ / NXCD) == xcd);
        col[i] = 0; val[i] = 0.0f;
        if (act[i]) {
            col[i] = cols[e0 + i * BLK];
            val[i] = vals[e0 + i * BLK];
        }
    }

    unsigned int pk[NI];
    int rk[NI];
    #pragma unroll
    for (int i = 0; i < NI; ++i) {
        int e = e0 + i * BLK;
        int k = e / NNZ_;
        unsigned int b  = __float_as_uint(val[i]);
        unsigned int rb = b + 0x1FFFu + ((b >> 14) & 1u);  // RNE to 9 mant
        int exp8 = (int)((rb >> 23) & 0xFF);
        unsigned int p = 0u;
        if (exp8 > 96)                                     // else flush to 0
            p = (b & 0x80000000u) | ((unsigned int)(exp8 - 96) << 26) |
                (((rb >> 14) & 0x1FFu) << 17);
        pk[i] = p | ((unsigned int)k << 15) | (unsigned int)col[i];
        rk[i] = row[i] * K_ + k;
    }

    int pos[NI];
    #pragma unroll
    for (int i = 0; i < NI; ++i)
        if (act[i]) pos[i] = atomicAdd(&cursor[rk[i]], 1);

    #pragma unroll
    for (int i = 0; i < NI; ++i)
        if (act[i]) cmeta[pos[i]] = pk[i];
}

// ---------------- iteration kernels ----------------

// Accumulate one <=64-edge chunk whose packed meta is ALREADY decoded into
// per-lane (c_l, v_l); lanes >= n hold (padc, 0). bf16 gather (ushort4),
// fp32 FMA, gathers batched BATCH-deep for memory-level parallelism.
template <int BATCH>
__device__ __forceinline__ void chunk_accum(
    int c_l, float v_l, int n, const ushort4* __restrict__ Xb,
    int sub, int q, float4& acc) {
    int iters = (n + 3) >> 2;
    int itersPad = (iters + BATCH - 1) & ~(BATCH - 1);  // <= 16
    for (int it0 = 0; it0 < itersPad; it0 += BATCH) {
        float   vv[BATCH];
        ushort4 xx[BATCH];
        #pragma unroll
        for (int u = 0; u < BATCH; ++u) {
            int j = 4 * (it0 + u) + sub;      // < 64
            int   c = __shfl(c_l, j, 64);
            vv[u]   = __shfl(v_l, j, 64);
            xx[u]   = Xb[c * (FEAT_ / 4) + q];
        }
        #pragma unroll
        for (int u = 0; u < BATCH; ++u) {
            acc.x += vv[u] * bf2f(xx[u].x);
            acc.y += vv[u] * bf2f(xx[u].y);
            acc.z += vv[u] * bf2f(xx[u].z);
            acc.w += vv[u] * bf2f(xx[u].w);
        }
    }
}

// Fallback (not pipelined): load+decode+accumulate windows [beg,end).
// Only runs for rare overflow chunks beyond the prefetched ones.
template <int BATCH>
__device__ __forceinline__ void tail_accum(
    const unsigned int* __restrict__ cmeta, const ushort4* __restrict__ Xb,
    int beg, int end, int lane, int sub, int q, int padc, float4& acc) {
    for (int eb = beg; eb < end; eb += 64) {
        int n = end - eb;
        if (n > 64) n = 64;
        int   c_l = padc;
        float v_l = 0.0f;
        if (lane < n) {
            unsigned int p = cmeta[eb + lane];
            decode_meta(p, c_l, v_l);
        }
        chunk_accum<BATCH>(c_l, v_l, n, Xb, sub, q, acc);
    }
}

__device__ __forceinline__ void butterfly4(float4& a) {
    #pragma unroll
    for (int m = 16; m <= 32; m <<= 1) {
        a.x += __shfl_xor(a.x, m, 64);
        a.y += __shfl_xor(a.y, m, 64);
        a.z += __shfl_xor(a.z, m, 64);
        a.w += __shfl_xor(a.w, m, 64);
    }
}

// wave per R_SP contiguous CSR rows (rowid = n*K+k); acc = (W_k @ X)[n];
// fused v-update into bf16 V_bf (layout [k][n]). FIRST: Y=0, X=F_bf.
// Meta for row r+1 prefetched during row r (R2 pipeline).
template <bool FIRST>
__global__ __launch_bounds__(BLK) void spmm_fused_kernel(
    const int* __restrict__ offs, const unsigned int* __restrict__ cmeta,
    const unsigned short* __restrict__ Xb,
    const float* __restrict__ d, unsigned short* __restrict__ V_bf) {
    int wave = (blockIdx.x * BLK + threadIdx.x) >> 6;
    int lane = threadIdx.x & 63;
    int sub  = lane >> 4, q = lane & 15;
    int base = wave * R_SP;
    if (base >= KN) return;
    int off_l = 0;
    if (lane <= R_SP) {
        int i = base + lane;
        if (i > KN) i = KN;
        off_l = offs[i];
    }
    const ushort4* X4 = (const ushort4*)Xb;
    ushort4* V4 = (ushort4*)V_bf;

    // prefetch row 0 meta (first chunk)
    unsigned int p_cur = 0u;
    {
        int b0 = __shfl(off_l, 0, 64), e0 = __shfl(off_l, 1, 64);
        int nn = e0 - b0;
        if (nn > 64) nn = 64;
        if (lane < nn) p_cur = cmeta[b0 + lane];
    }
    for (int r = 0; r < R_SP; ++r) {
        int w = base + r;                // rowid = n*K + k
        if (w >= KN) break;
        int k = w & (K_ - 1);
        int n = w >> 2;
        int beg = __shfl(off_l, r, 64);
        int end = __shfl(off_l, r + 1, 64);
        // issue next row's meta load (overlaps this row's gathers)
        unsigned int p_nxt = 0u;
        if (r + 1 < R_SP && w + 1 < KN) {
            int bn = __shfl(off_l, r + 1, 64), en = __shfl(off_l, r + 2, 64);
            int nn = en - bn;
            if (nn > 64) nn = 64;
            if (lane < nn) p_nxt = cmeta[bn + lane];
        }
        // decode current row's prefetched meta
        int n_e = end - beg;
        if (n_e > 64) n_e = 64;
        int   c_l = k * N_;              // pad col (valid after base adjust)
        float v_l = 0.0f;
        if (lane < n_e) decode_meta(p_cur, c_l, v_l);
        // decoded col' = k*N + col; recover shared-X indexing by base adjust
        const ushort4* X4m = X4 - (size_t)k * N_ * (FEAT_ / 4);
        float4 acc = {0.f, 0.f, 0.f, 0.f};
        chunk_accum<4>(c_l, v_l, n_e, X4m, sub, q, acc);
        if (end - beg > 64)              // astronomically rare
            tail_accum<4>(cmeta, X4m, beg + 64, end, lane, sub, q, k * N_, acc);
        p_cur = p_nxt;
        butterfly4(acc);                 // all lanes hold row sums
        if (sub == 0) {
            int idx4 = (k * N_ + n) * (FEAT_ / 4) + q;
            float thr = c_nu[k] * d[n];
            float4 y;
            if (FIRST) {
                y = make_float4(0.f, 0.f, 0.f, 0.f);
            } else {
                ushort4 vp = V4[idx4];   // v_{t-1}
                y.x = acc.x + bf2f(vp.x); y.y = acc.y + bf2f(vp.y);
                y.z = acc.z + bf2f(vp.z); y.w = acc.w + bf2f(vp.w);
            }
            ushort4 o;
            o.x = f2bf(y.x - softf(acc.x + y.x, thr));
            o.y = f2bf(y.y - softf(acc.y + y.y, thr));
            o.z = f2bf(y.z - softf(acc.z + y.z, thr));
            o.w = f2bf(y.w - softf(acc.w + y.w, thr));
            V4[idx4] = o;                // v_t
        }
    }
}

// wave per R_WT nodes: node n's edges over ALL k are one flat contiguous
// segment [offs[4n], offs[4n+4]) gathering V_bf[col'] directly.
// Segments are mean 64 +- 8 edges -> prefetch TWO 64-edge meta chunks for
// node r+1 during node r; chunks beyond 128 via tail_accum (negligible).
// U = (dm*F - acc)/(dm+1); fp32 U stored ONLY when LAST (d_out graded
// once); bf16 copy always (it feeds the next spmm's gathers).
template <bool LAST>
__global__ __launch_bounds__(BLK) void wtv_u_kernel(
    const int* __restrict__ offs, const unsigned int* __restrict__ cmeta,
    const unsigned short* __restrict__ V_bf,
    const float* __restrict__ F, const float* __restrict__ dm,
    float* __restrict__ U, unsigned short* __restrict__ U_bf) {
    int wave = (blockIdx.x * BLK + threadIdx.x) >> 6;
    int lane = threadIdx.x & 63;
    int sub  = lane >> 4, q = lane & 15;
    int base = wave * R_WT;
    if (base >= N_) return;
    int off_l = 0;
    if (lane <= K_ * R_WT) {             // 17 offsets
        int i = K_ * base + lane;
        if (i > KN) i = KN;
        off_l = offs[i];
    }
    const ushort4* V4 = (const ushort4*)V_bf;

    // prefetch node 0 meta (two chunks)
    unsigned int p0 = 0u, p1 = 0u;
    {
        int b0 = __shfl(off_l, 0, 64), e0 = __shfl(off_l, K_, 64);
        int nn = e0 - b0;
        if (lane < nn) p0 = cmeta[b0 + lane];
        if (64 + lane < nn) p1 = cmeta[b0 + 64 + lane];
    }
    for (int r = 0; r < R_WT; ++r) {
        int n = base + r;
        if (n >= N_) break;
        int beg = __shfl(off_l, K_ * r, 64);
        int end = __shfl(off_l, K_ * r + K_, 64);
        // issue next node's meta loads (overlap this node's gathers)
        unsigned int q0 = 0u, q1 = 0u;
        if (r + 1 < R_WT && n + 1 < N_) {
            int bn = __shfl(off_l, K_ * r + K_, 64);
            int en = __shfl(off_l, K_ * r + 2 * K_, 64);
            int nn = en - bn;
            if (lane < nn) q0 = cmeta[bn + lane];
            if (64 + lane < nn) q1 = cmeta[bn + 64 + lane];
        }
        int ne = end - beg;
        float4 acc = {0.f, 0.f, 0.f, 0.f};
        // chunk 0
        {
            int n0 = ne > 64 ? 64 : ne;
            int   c_l = 0;
            float v_l = 0.0f;
            if (lane < n0) decode_meta(p0, c_l, v_l);
            chunk_accum<8>(c_l, v_l, n0, V4, sub, q, acc);
        }
        // chunk 1
        if (ne > 64) {
            int n1 = ne - 64;
            if (n1 > 64) n1 = 64;
            int   c_l = 0;
            float v_l = 0.0f;
            if (lane < n1) decode_meta(p1, c_l, v_l);
            chunk_accum<2>(c_l, v_l, n1, V4, sub, q, acc);
        }
        if (ne > 128)                     // negligible tail
            tail_accum<2>(cmeta, V4, beg + 128, end, lane, sub, q, 0, acc);
        p0 = q0; p1 = q1;
        butterfly4(acc);
        if (sub == 0) {
            int idx4 = n * (FEAT_ / 4) + q;
            float dmv = dm[n];
            float r2 = 1.0f / (dmv + 1.0f);
            float4 f = ((const float4*)F)[idx4];
            float4 o;
            o.x = (dmv * f.x - acc.x) * r2; o.y = (dmv * f.y - acc.y) * r2;
            o.z = (dmv * f.z - acc.z) * r2; o.w = (dmv * f.w - acc.w) * r2;
            if (LAST) ((float4*)U)[idx4] = o;
            ushort4 ob;
            ob.x = f2bf(o.x); ob.y = f2bf(o.y);
            ob.z = f2bf(o.z); ob.w = f2bf(o.w);
            ((ushort4*)U_bf)[idx4] = ob;
        }
    }
}

extern "C" void kernel_launch(void* const* d_in, const int* in_sizes, int n_in,
                              void* d_out, int out_size, void* d_ws, size_t ws_size,
                              hipStream_t stream) {
    const float* F      = (const float*)d_in[0];
    const int*   w_rows = (const int*)d_in[1];
    const int*   w_cols = (const int*)d_in[2];
    const float* w_vals = (const float*)d_in[3];
    const float* d      = (const float*)d_in[4];
    const float* mask   = (const float*)d_in[5];
    float* U = (float*)d_out;

    // workspace layout (~29 MB)
    unsigned int* cmeta  = (unsigned int*)d_ws;               // NEDGE u32
    unsigned short* V_bf = (unsigned short*)(cmeta + NEDGE);  // KN*FEAT us
    unsigned short* U_bf = V_bf + (size_t)KN * FEAT_;         // NF us
    unsigned short* F_bf = U_bf + NF;                         // NF us
    float* dm     = (float*)(F_bf + NF);                      // N
    int*   cnt8   = (int*)(dm + N_);                          // NCPY*KN
    int*   loc    = cnt8 + NCPY * KN;                         // KN
    int*   bsum   = loc + KN;                                 // pad 512
    int*   offs   = bsum + 512;                               // KN+1
    int*   cursor = offs + KN + 1;                            // KN

    const int gEdge = NEDGE / BLK;                // 5000
    const int gNF4  = (NF / 4) / BLK;             // 1250

    // ---- CSR build + precompute ----
    hipMemsetAsync(cnt8, 0, (size_t)NCPY * KN * 4, stream);
    precompute_kernel<<<gNF4, BLK, 0, stream>>>(F, d, mask, dm, F_bf);
    hist_kernel<<<gEdge, BLK, 0, stream>>>(w_rows, cnt8);
    scan1_kernel<<<NSB, 256, 0, stream>>>(cnt8, loc, bsum);
    scan2_kernel<<<1, 512, 0, stream>>>(bsum);
    scan3_kernel<<<NSB, 256, 0, stream>>>(loc, bsum, offs, cursor);
    scatter_kernel<<<NVB * NXCD, BLK, 0, stream>>>(w_rows, w_cols, w_vals,
                                                   cursor, cmeta);

    // ---- iterations ----
    spmm_fused_kernel<true><<<NB_SP, BLK, 0, stream>>>(offs, cmeta, F_bf, d, V_bf);
    for (int it = 0; it < NITER; ++it) {
        if (it < NITER - 1) {
            wtv_u_kernel<false><<<NB_WT, BLK, 0, stream>>>(offs, cmeta, V_bf,
                                                           F, dm, U, U_bf);
            spmm_fused_kernel<false><<<NB_SP, BLK, 0, stream>>>(offs, cmeta,
                                                                U_bf, d, V_bf);
        } else {
            wtv_u_kernel<true><<<NB_WT, BLK, 0, stream>>>(offs, cmeta, V_bf,
                                                          F, dm, U, U_bf);
        }
    }
}